// Round 1
// baseline (227.469 us; speedup 1.0000x reference)
//
#include <hip/hip_runtime.h>

// GlobalShift2dV2Portion: x (16, 512, 64, 64) f32.
// ch < 256  : identity copy.
// ch >= 256 : 64x64 image = 4x4 grid of 16x16 blocks; block t_out=(h/16)*4+(w/16)
//             reads from block t_in = (s + t_out) % 16, s = (ch-256)/16.
// The permutation is entirely within one (b,ch) image (16 KiB).
//
// V3: one 256-thread workgroup per image. Shifted half stages the image in LDS
// so BOTH global reads and writes are contiguous 1 KiB per wave-instruction
// (V2's gather reads were 16 scattered 64B segments per instruction).
// Non-temporal stores keep the write stream from evicting the L3-resident input.

#define CC   512
#define IMG4 1024   // 64*64/4 float4 per (b,ch) image

typedef float f32x4 __attribute__((ext_vector_type(4)));

__global__ __launch_bounds__(256) void GlobalShift2dV2Portion_kernel(
    const f32x4* __restrict__ in, f32x4* __restrict__ out) {
  __shared__ f32x4 lds[IMG4];                 // 16 KiB
  const int bc   = blockIdx.x;                // b*512 + ch
  const int ch   = bc & (CC - 1);
  const int base = bc << 10;                  // bc * IMG4
  const int tid  = threadIdx.x;

  if (ch < CC / 2) {
    // identity half: pure coalesced copy, 4 float4 per thread
#pragma unroll
    for (int k = 0; k < 4; ++k) {
      const int o = (k << 8) + tid;
      __builtin_nontemporal_store(in[base + o], &out[base + o]);
    }
    return;
  }

  // stage the whole image in LDS with fully-coalesced loads
#pragma unroll
  for (int k = 0; k < 4; ++k) {
    const int o = (k << 8) + tid;
    lds[o] = in[base + o];
  }
  __syncthreads();

  const int s = (ch - CC / 2) >> 4;           // [0,16)
#pragma unroll
  for (int k = 0; k < 4; ++k) {
    const int o     = (k << 8) + tid;         // output float4 index in image
    const int w4    = o & 15;                 // w/4 within row
    const int h     = o >> 4;                 // row
    const int t_in  = (s + ((h >> 4) << 2) + (w4 >> 2)) & 15;  // source block
    const int h_in  = ((t_in >> 2) << 4) | (h & 15);
    const int w4_in = ((t_in & 3) << 2) | (w4 & 3);
    __builtin_nontemporal_store(lds[(h_in << 4) | w4_in], &out[base + o]);
  }
}

extern "C" void kernel_launch(void* const* d_in, const int* in_sizes, int n_in,
                              void* d_out, int out_size, void* d_ws, size_t ws_size,
                              hipStream_t stream) {
  const f32x4* in = (const f32x4*)d_in[0];
  f32x4* out = (f32x4*)d_out;
  const int blocks = in_sizes[0] / (IMG4 * 4);   // = 16*512 = 8192 images
  GlobalShift2dV2Portion_kernel<<<blocks, 256, 0, stream>>>(in, out);
}

// Round 2
// 226.947 us; speedup vs baseline: 1.0023x; 1.0023x over previous
//
#include <hip/hip_runtime.h>

// GlobalShift2dV2Portion: x (16, 512, 64, 64) f32.
// ch < 256  : identity copy.
// ch >= 256 : 64x64 image = 4x4 grid of 16x16 blocks; block t_out=(h/16)*4+(w/16)
//             reads from block t_in = (s + t_out) % 16, s = (ch-256)/16.
//
// V4: one 256-thread WG per (b,ch) image (16 KiB), 4 float4 per thread.
//  - direct gather reads (V2 pattern: 64B segments, L2-absorbed, no over-fetch)
//  - output-coalesced plain stores (V3's LDS+nt regressed; reverted)
//  - s=0 makes the shift formula the identity, so ONE unified path, no branch
//  - 4 independent loads in flight per thread (4x MLP of V2), 8192 blocks
//    instead of 32768 (less dispatch churn)

#define CC 512

typedef float f32x4 __attribute__((ext_vector_type(4)));

__global__ __launch_bounds__(256) void GlobalShift2dV2Portion_kernel(
    const f32x4* __restrict__ in, f32x4* __restrict__ out) {
  const int bc   = blockIdx.x;            // b*512 + ch
  const int ch   = bc & (CC - 1);
  const int base = bc << 10;              // bc * 1024 float4
  const int tid  = threadIdx.x;

  const int sh = (ch >= CC / 2) ? ((ch - CC / 2) >> 4) : 0;  // 0 => identity
  const int w4 = tid & 15;                // w/4 within row
  const int h0 = tid >> 4;                // row within 16-row stripe
  const int b0 = w4 >> 2;                 // w-block of output
  const int wl = w4 & 3;                  // f4 within w-block

#pragma unroll
  for (int k = 0; k < 4; ++k) {           // k = h-block of output (h = k*16+h0)
    const int t_in  = (sh + (k << 2) + b0) & 15;       // source 16x16 block
    const int h_in  = ((t_in >> 2) << 4) | h0;
    const int w4_in = ((t_in & 3) << 2) | wl;
    // output index base + k*256 + tid : fully coalesced per instruction
    out[base + (k << 8) + tid] = in[base + (h_in << 4) + w4_in];
  }
}

extern "C" void kernel_launch(void* const* d_in, const int* in_sizes, int n_in,
                              void* d_out, int out_size, void* d_ws, size_t ws_size,
                              hipStream_t stream) {
  const f32x4* in = (const f32x4*)d_in[0];
  f32x4* out = (f32x4*)d_out;
  const int blocks = in_sizes[0] / (1024 * 4);   // 16*512 = 8192 images
  GlobalShift2dV2Portion_kernel<<<blocks, 256, 0, stream>>>(in, out);
}

// Round 3
// 220.439 us; speedup vs baseline: 1.0319x; 1.0295x over previous
//
#include <hip/hip_runtime.h>

// GlobalShift2dV2Portion: x (16, 512, 64, 64) f32.
// ch < 256  : identity. ch >= 256 : 4x4 grid of 16x16 blocks, block ring
// rotated by s = (ch-256)/16 (t_in = (s + t_out) % 16).
//
// V5: V2's winning skeleton (1 float4/thread, 256-thread blocks, 32768 blocks)
// with wave-level "super-row" lane assignment. Super-row h0 = image rows
// {h0, 16+h0, 32+h0, 48+h0} = 1 KiB = one wave64 of float4. In super-row
// float4 slots q, the block rotation is q_in = (q_out + 4s) & 63 — a bijection
// WITHIN the wave. So each wave's read-address union == its write-address
// union == 8 full 128B lines, for every s: both streams perfectly coalesced
// at line granularity (V2 touched ~12 lines per wave on reads when s%4 != 0).

#define CC 512

typedef float f32x4 __attribute__((ext_vector_type(4)));

__global__ __launch_bounds__(256) void GlobalShift2dV2Portion_kernel(
    const f32x4* __restrict__ in, f32x4* __restrict__ out) {
  const int i  = blockIdx.x * 256 + threadIdx.x;  // global float4 slot
  const int l  = i & 63;          // slot within super-row (lane)
  const int h0 = (i >> 6) & 15;   // super-row (row within 16-row stripe)
  const int bc = i >> 10;         // b*512 + ch
  const int ch = bc & (CC - 1);

  const int sh = (ch >= CC / 2) ? ((ch - CC / 2) >> 4) : 0;  // 0 => identity
  const int q  = (l + (sh << 2)) & 63;   // rotated input slot (bijection in wave)

  const int base = bc << 10;
  // slot -> in-image float4 offset: chunk = slot>>4 selects the 16-row stripe,
  // row = h0, pos = slot&15 within the 256B row.
  const int o4 = ((l >> 4) << 8) | (h0 << 4) | (l & 15);
  const int i4 = ((q >> 4) << 8) | (h0 << 4) | (q & 15);

  out[base + o4] = in[base + i4];
}

extern "C" void kernel_launch(void* const* d_in, const int* in_sizes, int n_in,
                              void* d_out, int out_size, void* d_ws, size_t ws_size,
                              hipStream_t stream) {
  const f32x4* in = (const f32x4*)d_in[0];
  f32x4* out = (f32x4*)d_out;
  const int total4 = in_sizes[0] / 4;       // 8,388,608 float4
  const int blocks = total4 / 256;          // 32,768
  GlobalShift2dV2Portion_kernel<<<blocks, 256, 0, stream>>>(in, out);
}

// Round 4
// 219.189 us; speedup vs baseline: 1.0378x; 1.0057x over previous
//
#include <hip/hip_runtime.h>

// GlobalShift2dV2Portion: x (16, 512, 64, 64) f32.
// ch < 256  : identity. ch >= 256 : 4x4 grid of 16x16 blocks, block ring
// rotated by s = (ch-256)/16 (t_in = (s + t_out) % 16).
//
// V6 = V5 (wave-bijective super-row addressing, both streams 128B-line
// coalesced for every shift) + NON-TEMPORAL STORES.
// Rationale: input (128 MiB) is L3-resident across bench iterations; the
// write stream's cache allocation (input+output = 256 MiB = full L3) evicts
// it. nt-stores stream writes past L2/L3, keeping reads at L3 bandwidth.
// (V3's nt test was confounded with the LDS restructure; this is the clean A/B.)

#define CC 512

typedef float f32x4 __attribute__((ext_vector_type(4)));

__global__ __launch_bounds__(256) void GlobalShift2dV2Portion_kernel(
    const f32x4* __restrict__ in, f32x4* __restrict__ out) {
  const int i  = blockIdx.x * 256 + threadIdx.x;  // global float4 slot
  const int l  = i & 63;          // slot within super-row (lane)
  const int h0 = (i >> 6) & 15;   // super-row (row within 16-row stripe)
  const int bc = i >> 10;         // b*512 + ch
  const int ch = bc & (CC - 1);

  const int sh = (ch >= CC / 2) ? ((ch - CC / 2) >> 4) : 0;  // 0 => identity
  const int q  = (l + (sh << 2)) & 63;   // rotated input slot (bijection in wave)

  const int base = bc << 10;
  // slot -> in-image float4 offset: chunk = slot>>4 selects the 16-row stripe,
  // row = h0, pos = slot&15 within the 256B row.
  const int o4 = ((l >> 4) << 8) | (h0 << 4) | (l & 15);
  const int i4 = ((q >> 4) << 8) | (h0 << 4) | (q & 15);

  __builtin_nontemporal_store(in[base + i4], &out[base + o4]);
}

extern "C" void kernel_launch(void* const* d_in, const int* in_sizes, int n_in,
                              void* d_out, int out_size, void* d_ws, size_t ws_size,
                              hipStream_t stream) {
  const f32x4* in = (const f32x4*)d_in[0];
  f32x4* out = (f32x4*)d_out;
  const int total4 = in_sizes[0] / 4;       // 8,388,608 float4
  const int blocks = total4 / 256;          // 32,768
  GlobalShift2dV2Portion_kernel<<<blocks, 256, 0, stream>>>(in, out);
}